// Round 1
// baseline (484.031 us; speedup 1.0000x reference)
//
#include <hip/hip_runtime.h>
#include <hip/hip_bf16.h>
#include <cstdint>

typedef __attribute__((ext_vector_type(8))) short bf16x8;
typedef __attribute__((ext_vector_type(4))) float f32x4;

#define H_DIM 1024
#define B_DIM 32
#define L_DIM 2048
#define NT 32                   // K-tiles of 64 (K_TOT = 2048)

__device__ __forceinline__ void gload16(const void* g, void* l) {
  __builtin_amdgcn_global_load_lds(
      (const __attribute__((address_space(1))) unsigned int*)g,
      (__attribute__((address_space(3))) unsigned int*)l, 16, 0, 0);
}

#define VMCNT(n) asm volatile("s_waitcnt vmcnt(" #n ")" ::: "memory")
#define LGKM0 asm volatile("s_waitcnt lgkmcnt(0)" ::: "memory")
#define SBAR __builtin_amdgcn_sched_barrier(0)
#define BAR do { SBAR; __builtin_amdgcn_s_barrier(); SBAR; } while (0)

// fast tanh: 1 - 2/(exp(2x)+1). Saturates correctly; no NaN. Validated R12.
__device__ __forceinline__ float tanh_fast(float x) {
  return 1.f - 2.f / (__expf(2.f * x) + 1.f);
}

// 8x f32 -> bf16x8 (RNE, identical rounding to the old convert_all pass)
__device__ __forceinline__ bf16x8 pack8(float4 a, float4 b) {
  union { __hip_bfloat16 h; short s; } u;
  bf16x8 v;
  u.h = __float2bfloat16(a.x); v[0] = u.s;
  u.h = __float2bfloat16(a.y); v[1] = u.s;
  u.h = __float2bfloat16(a.z); v[2] = u.s;
  u.h = __float2bfloat16(a.w); v[3] = u.s;
  u.h = __float2bfloat16(b.x); v[4] = u.s;
  u.h = __float2bfloat16(b.y); v[5] = u.s;
  u.h = __float2bfloat16(b.z); v[6] = u.s;
  u.h = __float2bfloat16(b.w); v[7] = u.s;
  return v;
}

// ---------------------------------------------------------------- weights-only convert (8 MB traffic, ~3 us)
__global__ void __launch_bounds__(256)
convert_w(const float* __restrict__ Wk, const float* __restrict__ Wq,
          __hip_bfloat16* __restrict__ wkb, __hip_bfloat16* __restrict__ wqb) {
  const int i = blockIdx.x * 256 + threadIdx.x;   // 0..524287 float4 chunks
  const float* src = (i < 262144) ? Wk : Wq;
  __hip_bfloat16* dst = (i < 262144) ? wkb : wqb;
  const int off = i & 262143;
  float4 v = ((const float4*)src)[off];
  __hip_bfloat16 h[4];
  h[0] = __float2bfloat16(v.x);
  h[1] = __float2bfloat16(v.y);
  h[2] = __float2bfloat16(v.z);
  h[3] = __float2bfloat16(v.w);
  *(uint2*)(dst + (size_t)off * 4) = *(const uint2*)h;
}

// ---------------------------------------------------------------- 256x256x64 8-wave GEMM (R13: fused f32->bf16 A-staging)
// R11 1-barrier-per-phase skeleton kept. A path now reg-stages f32 key/query:
//   P1: issue 4x global_load_dwordx4 (A-kk0 of t+1, f32) -> ra
//   P2: stage B-kk0(t+1) via gload_lds ; cvt ra -> ds_write_b128 (swizzled
//       dest) ; VMCNT(2) ; lgkmcnt(0) ; BAR      (phase length ~1270cy > HBM lat)
//   P3/P4: same for kk1. B path unchanged (gload_lds, pre-swizzled source).
// vmcnt deadlines (queue order A0,B0,A1,B1 per tile): the cvt at P2/P4 is
// dependency-forced to wait vmcnt<=2, which drains the previous B stage before
// the barrier its readers sit behind; VMCNT(2) pins the B gload_lds on the
// correct side. lgkmcnt(0) before P2/P4 barriers publishes the ds_writes.
// WAR: every staged region's readers completed >=1 barrier earlier (parity flip).
// LDS (128 KiB): A parity p at p*32768 (two 16KB halves [kk][256r][32c] bf16,
// 64B rows); B at 65536 + p*32768. Swizzle: byte ^= ((byte>>7)&3)<<4 — applied
// on ds_write DEST for A, on global SOURCE for B (gload_lds dest stays linear).
__global__ void __launch_bounds__(512, 2)
gemm_score_kernel(const float* __restrict__ key,
                  const float* __restrict__ query,
                  const __hip_bfloat16* __restrict__ wkb,
                  const __hip_bfloat16* __restrict__ wqb,
                  const float* __restrict__ bias,
                  const float* __restrict__ w_score,
                  float* __restrict__ spart) {
  extern __shared__ __align__(1024) char lds[];

  // bijective XCD swizzle: nwg=1024 (%8==0), chunk=128
  const int d = blockIdx.x;
  const int orig = (d & 7) * 128 + (d >> 3);
  const int mt = orig >> 2;  // 0..255
  const int nt = orig & 3;   // 0..3

  const int tid = threadIdx.x;
  const int lane = tid & 63;
  const int w = tid >> 6;
  const int wr = w >> 2;     // 0..1
  const int wc = w & 3;      // 0..3

  // ---- staging precompute: per 16KB half, per thread 2 chunks of 16B (bf16).
  // B: linear LDS dest + pre-swizzled bf16 global source (gload_lds).
  // A: swizzled LDS dest + linear f32 global source (reg-staged).
  int dstA[2], dstB[2];
  size_t asrcg[2], boffg[2];
#pragma unroll
  for (int i = 0; i < 2; ++i) {
    int p = (i * 512 + tid) * 16;
    int row = p >> 6;                       // 0..255
    int q = p ^ (((p >> 7) & 3) << 4);
    dstB[i] = p;
    boffg[i] = (size_t)(nt * 256 + row) * 1024 + ((q & 63) >> 1);
    dstA[i] = q;
    asrcg[i] = (size_t)(mt * 256 + row) * 1024 + ((p & 63) >> 1);
  }

  float4 ra[4];   // in-flight A stage (16 VGPR), live for one phase at a time

#define ISSUE_A(kk, tt) do {                                                   \
    const float* sp_ = ((tt) * 64 < 1024) ? key : query;                       \
    const int kb_ = (((tt) * 64) & 1023) + (kk) * 32;                          \
    _Pragma("unroll") for (int i = 0; i < 2; ++i) {                            \
      const float* s0_ = sp_ + asrcg[i] + kb_;                                 \
      ra[2 * i]     = *(const float4*)(s0_);                                   \
      ra[2 * i + 1] = *(const float4*)(s0_ + 4);                               \
    }                                                                          \
  } while (0)
#define WRITE_A(kk, tt) do {                                                   \
    char* db_ = lds + ((tt) & 1) * 32768 + (kk) * 16384;                       \
    _Pragma("unroll") for (int i = 0; i < 2; ++i)                              \
      *(bf16x8*)(db_ + dstA[i]) = pack8(ra[2 * i], ra[2 * i + 1]);             \
  } while (0)
#define STAGE_B(kk, tt) do {                                                   \
    const __hip_bfloat16* sp_ = ((tt) * 64 < 1024) ? wkb : wqb;                \
    const int kb_ = (((tt) * 64) & 1023) + (kk) * 32;                          \
    char* db_ = lds + 65536 + ((tt) & 1) * 32768 + (kk) * 16384;               \
    gload16(sp_ + boffg[0] + kb_, db_ + dstB[0]);                              \
    gload16(sp_ + boffg[1] + kb_, db_ + dstB[1]);                              \
  } while (0)

  // ---- fragment ds_read byte offsets (within parity base)
  const int frow = lane & 15;
  const int koffb = (lane >> 4) * 16;
  int aoff[8][2], boff[4][2];
#pragma unroll
  for (int m = 0; m < 8; ++m) {
    int r = wr * 128 + m * 16 + frow;
#pragma unroll
    for (int kk = 0; kk < 2; ++kk) {
      int byte = r * 64 + koffb;
      aoff[m][kk] = kk * 16384 + (byte ^ (((byte >> 7) & 3) << 4));
    }
  }
#pragma unroll
  for (int n = 0; n < 4; ++n) {
    int r = wc * 64 + n * 16 + frow;
#pragma unroll
    for (int kk = 0; kk < 2; ++kk) {
      int byte = r * 64 + koffb;
      boff[n][kk] = 65536 + kk * 16384 + (byte ^ (((byte >> 7) & 3) << 4));
    }
  }

  f32x4 acc[8][4] = {};

  // ---- prologue: stage tile 0 (A serial through ra; latency exposed once)
  ISSUE_A(0, 0);
  STAGE_B(0, 0); STAGE_B(1, 0);
  WRITE_A(0, 0);            // dep-forced vmcnt drains A0 loads
  ISSUE_A(1, 0);
  WRITE_A(1, 0);
  VMCNT(0);                 // B0,B1 landed
  LGKM0;                    // ds_writes visible
  BAR;

#define TILE_STEP(T, DO_S)                                                     \
  do {                                                                         \
    const int t_ = (T);                                                        \
    const char* Ab = lds + (t_ & 1) * 32768;                                   \
    bf16x8 a0[4], a1[4], b0[4], b1[4];                                         \
    /* P1: reads kk0 m0-3 + B kk0 ; issue A-kk0(t+1) ; BAR ; MFMA */           \
    _Pragma("unroll") for (int m = 0; m < 4; ++m)                              \
        a0[m] = *(const bf16x8*)(Ab + aoff[m][0]);                             \
    _Pragma("unroll") for (int n = 0; n < 4; ++n)                              \
        b0[n] = *(const bf16x8*)(Ab + boff[n][0]);                             \
    if (DO_S) { ISSUE_A(0, t_ + 1); }                                          \
    BAR;                                                                       \
    __builtin_amdgcn_s_setprio(1);                                             \
    _Pragma("unroll") for (int m = 0; m < 4; ++m)                              \
      _Pragma("unroll") for (int n = 0; n < 4; ++n)                            \
        acc[m][n] = __builtin_amdgcn_mfma_f32_16x16x32_bf16(                   \
            a0[m], b0[n], acc[m][n], 0, 0, 0);                                 \
    __builtin_amdgcn_s_setprio(0);                                             \
    /* P2: reads kk0 m4-7 ; stage B-kk0(t+1) ; write A-kk0(t+1) ; BAR ; MFMA */\
    _Pragma("unroll") for (int m = 0; m < 4; ++m)                              \
        a1[m] = *(const bf16x8*)(Ab + aoff[4 + m][0]);                         \
    if (DO_S) { STAGE_B(0, t_ + 1); WRITE_A(0, t_ + 1); VMCNT(2); LGKM0; }     \
    else { VMCNT(0); }                                                         \
    BAR;                                                                       \
    __builtin_amdgcn_s_setprio(1);                                             \
    _Pragma("unroll") for (int m = 0; m < 4; ++m)                              \
      _Pragma("unroll") for (int n = 0; n < 4; ++n)                            \
        acc[4 + m][n] = __builtin_amdgcn_mfma_f32_16x16x32_bf16(               \
            a1[m], b0[n], acc[4 + m][n], 0, 0, 0);                             \
    __builtin_amdgcn_s_setprio(0);                                             \
    /* P3: reads kk1 m0-3 + B kk1 ; issue A-kk1(t+1) ; BAR ; MFMA */           \
    _Pragma("unroll") for (int m = 0; m < 4; ++m)                              \
        a0[m] = *(const bf16x8*)(Ab + aoff[m][1]);                             \
    _Pragma("unroll") for (int n = 0; n < 4; ++n)                              \
        b1[n] = *(const bf16x8*)(Ab + boff[n][1]);                             \
    if (DO_S) { ISSUE_A(1, t_ + 1); }                                          \
    BAR;                                                                       \
    __builtin_amdgcn_s_setprio(1);                                             \
    _Pragma("unroll") for (int m = 0; m < 4; ++m)                              \
      _Pragma("unroll") for (int n = 0; n < 4; ++n)                            \
        acc[m][n] = __builtin_amdgcn_mfma_f32_16x16x32_bf16(                   \
            a0[m], b1[n], acc[m][n], 0, 0, 0);                                 \
    __builtin_amdgcn_s_setprio(0);                                             \
    /* P4: reads kk1 m4-7 ; stage B-kk1(t+1) ; write A-kk1(t+1) ; BAR ; MFMA */\
    _Pragma("unroll") for (int m = 0; m < 4; ++m)                              \
        a1[m] = *(const bf16x8*)(Ab + aoff[4 + m][1]);                         \
    if (DO_S) { STAGE_B(1, t_ + 1); WRITE_A(1, t_ + 1); VMCNT(2); LGKM0; BAR; }\
    __builtin_amdgcn_s_setprio(1);                                             \
    _Pragma("unroll") for (int m = 0; m < 4; ++m)                              \
      _Pragma("unroll") for (int n = 0; n < 4; ++n)                            \
        acc[4 + m][n] = __builtin_amdgcn_mfma_f32_16x16x32_bf16(               \
            a1[m], b1[n], acc[4 + m][n], 0, 0, 0);                             \
    __builtin_amdgcn_s_setprio(0);                                             \
  } while (0)

#pragma unroll 1
  for (int t = 0; t < NT - 1; ++t)
    TILE_STEP(t, true);
  TILE_STEP(NT - 1, false);

  // ---- epilogue: fast-tanh + w_score partial dot, reduce over n (lane&15)
  const int nbase = nt * 256 + wc * 64;
  float wj[4], bj[4];
#pragma unroll
  for (int j = 0; j < 4; ++j) {
    int n = nbase + j * 16 + frow;
    wj[j] = w_score[n];
    bj[j] = bias[n];
  }
  const int mbase = mt * 256 + wr * 128;
  const int pidx = nt * 4 + wc;
#pragma unroll
  for (int i = 0; i < 8; ++i) {
#pragma unroll
    for (int r = 0; r < 4; ++r) {
      float v = 0.f;
#pragma unroll
      for (int j = 0; j < 4; ++j) v += wj[j] * tanh_fast(acc[i][j][r] + bj[j]);
      v += __shfl_xor(v, 1);
      v += __shfl_xor(v, 2);
      v += __shfl_xor(v, 4);
      v += __shfl_xor(v, 8);
      if (frow == 0) {
        int m = mbase + i * 16 + (lane >> 4) * 4 + r;
        spart[(size_t)m * 16 + pidx] = v;
      }
    }
  }
#undef TILE_STEP
#undef STAGE_B
#undef WRITE_A
#undef ISSUE_A
}

// ---------------------------------------------------------------- softmax over L per batch
__global__ void __launch_bounds__(256)
softmax_kernel(const float* __restrict__ spart, const float* __restrict__ b_score_p,
               float* __restrict__ attn) {
  const int b = blockIdx.x;
  const int tid = threadIdx.x;
  const int lane = tid & 63;
  const int w = tid >> 6;
  const float bsc = b_score_p[0];
  __shared__ float red[8];
  float s[8];
  float lmax = -1e30f;
#pragma unroll
  for (int u = 0; u < 8; ++u) {
    const int l = u * 256 + tid;
    const float4* p = (const float4*)(spart + ((size_t)b * 2048 + l) * 16);
    float4 a = p[0], c = p[1], d2 = p[2], e2 = p[3];
    float sum = bsc + a.x + a.y + a.z + a.w + c.x + c.y + c.z + c.w +
                d2.x + d2.y + d2.z + d2.w + e2.x + e2.y + e2.z + e2.w;
    s[u] = sum;
    lmax = fmaxf(lmax, sum);
  }
#pragma unroll
  for (int m = 32; m >= 1; m >>= 1) lmax = fmaxf(lmax, __shfl_xor(lmax, m));
  if (lane == 0) red[w] = lmax;
  __syncthreads();
  const float gmax = fmaxf(fmaxf(red[0], red[1]), fmaxf(red[2], red[3]));
  float e[8];
  float lsum = 0.f;
#pragma unroll
  for (int u = 0; u < 8; ++u) {
    e[u] = expf(s[u] - gmax);
    lsum += e[u];
  }
#pragma unroll
  for (int m = 32; m >= 1; m >>= 1) lsum += __shfl_xor(lsum, m);
  if (lane == 0) red[4 + w] = lsum;
  __syncthreads();
  const float inv = 1.f / (red[4] + red[5] + red[6] + red[7]);
#pragma unroll
  for (int u = 0; u < 8; ++u) attn[(size_t)b * 2048 + u * 256 + tid] = e[u] * inv;
}

// ---------------------------------------------------------------- context (f32 key, 32B/lane loads)
// Block (lc, b): 64 l-rows x 1024 h. Thread (ro = tid>>7, h0 = (tid&127)*8)
// accumulates 8 h-values over its 32 l-rows (l = 2*li + ro). 2x16B/lane
// coalesced. 1024 blocks = 4/CU for latency hiding at 268 MB volume.
__global__ void __launch_bounds__(256)
ctx_part_kernel(const float* __restrict__ key, const float* __restrict__ attn,
                float* __restrict__ pctx) {
  __shared__ float a_sh[64];
  const int lc = blockIdx.x;   // 0..31
  const int b = blockIdx.y;    // 0..31
  const int tid = threadIdx.x;
  if (tid < 64) a_sh[tid] = attn[(size_t)b * 2048 + lc * 64 + tid];
  __syncthreads();
  const int ro = tid >> 7;            // 0..1
  const int h0 = (tid & 127) * 8;
  float ax[8] = {};
  const float* base =
      key + ((size_t)b * 2048 + lc * 64 + ro) * 1024 + h0;
#pragma unroll 4
  for (int li = 0; li < 32; ++li) {
    float a = a_sh[li * 2 + ro];
    float4 v0 = *(const float4*)(base + (size_t)li * 2048);
    float4 v1 = *(const float4*)(base + (size_t)li * 2048 + 4);
    ax[0] += a * v0.x; ax[1] += a * v0.y; ax[2] += a * v0.z; ax[3] += a * v0.w;
    ax[4] += a * v1.x; ax[5] += a * v1.y; ax[6] += a * v1.z; ax[7] += a * v1.w;
  }
  float* out = pctx + (((size_t)b * 32 + lc) * 2 + ro) * 1024 + h0;
#pragma unroll
  for (int j = 0; j < 8; ++j) out[j] = ax[j];
}

__global__ void __launch_bounds__(256)
ctx_reduce_kernel(const float* __restrict__ pctx, float* __restrict__ ctx) {
  const int idx = blockIdx.x * 256 + threadIdx.x;  // 0..32767
  const int b = idx >> 10, h = idx & 1023;
  float s = 0.f;
#pragma unroll
  for (int q = 0; q < 64; ++q) s += pctx[((size_t)b * 64 + q) * 1024 + h];
  ctx[idx] = s;
}

// ---------------------------------------------------------------- launch
extern "C" void kernel_launch(void* const* d_in, const int* in_sizes, int n_in,
                              void* d_out, int out_size, void* d_ws, size_t ws_size,
                              hipStream_t stream) {
  const float* query = (const float*)d_in[0];
  const float* key = (const float*)d_in[1];
  const float* Wq = (const float*)d_in[2];
  const float* Wk = (const float*)d_in[3];
  const float* bias = (const float*)d_in[4];
  const float* w_score = (const float*)d_in[5];
  const float* b_score = (const float*)d_in[6];

  float* out_ctx = (float*)d_out;
  float* out_attn = out_ctx + 32768;

  char* ws = (char*)d_ws;
  __hip_bfloat16* wkb = (__hip_bfloat16*)ws;                    // 2 MiB
  __hip_bfloat16* wqb = (__hip_bfloat16*)(ws + 2097152);        // 2 MiB
  float* spart = (float*)(ws + 4194304);                        // 4 MiB
  float* pctx = (float*)(ws + 8388608);                         // 8 MiB

  hipFuncSetAttribute((const void*)gemm_score_kernel,
                      hipFuncAttributeMaxDynamicSharedMemorySize, 131072);

  convert_w<<<2048, 256, 0, stream>>>(Wk, Wq, wkb, wqb);

  gemm_score_kernel<<<1024, 512, 131072, stream>>>(key, query, wkb, wqb, bias,
                                                   w_score, spart);

  softmax_kernel<<<B_DIM, 256, 0, stream>>>(spart, b_score, out_attn);

  ctx_part_kernel<<<dim3(32, B_DIM), 256, 0, stream>>>(key, out_attn, pctx);
  ctx_reduce_kernel<<<128, 256, 0, stream>>>(pctx, out_ctx);
}